// Round 10
// baseline (7332.478 us; speedup 1.0000x reference)
//
#include <hip/hip_runtime.h>
#include <math.h>

// LSTM: B=64, T=784, I=1, H=600.
// r4/r9 hybrid: 200 WGs = 50 cell-groups x 4 batch-groups, 12 cells x 16
// batches per WG. pk-FMA GEMV (r9-verified). Fused per-producer wait+stage
// with conflict-free write mapping. Per-wave drained atomicAdd flags
// (wave-coalesced per m20) -> 2 barriers/step, shorter signal chain.
#define BB 64
#define TT 784
#define HH 600
#define CG 50           // cell-groups
#define SGN 4           // batch-groups
#define CPW 12          // cells per WG  -> 48 gate-rows
#define BW 16           // batches per WG
#define NWG (CG*SGN)    // 200
#define BLOCK 512       // 8 waves; wave owns 6 gate-rows; lane=(bh:2 x kh:32)
#define HB4 (BW*150)    // 2400 float4 of h per WG
#define LDS_BYTES (84*1024)   // force 1 WG/CU

typedef float f2v __attribute__((ext_vector_type(2)));

// five pipelined cache-bypassing 16B loads (one IF$ latency) -- t=0 staging
__device__ __forceinline__ void ldg5_bypass(const float4* g0, const float4* g1,
                                            const float4* g2, const float4* g3,
                                            const float4* g4,
                                            float4& a, float4& b, float4& c,
                                            float4& d, float4& e) {
    asm volatile(
        "global_load_dwordx4 %0, %5, off sc0 sc1\n\t"
        "global_load_dwordx4 %1, %6, off sc0 sc1\n\t"
        "global_load_dwordx4 %2, %7, off sc0 sc1\n\t"
        "global_load_dwordx4 %3, %8, off sc0 sc1\n\t"
        "global_load_dwordx4 %4, %9, off sc0 sc1\n\t"
        "s_waitcnt vmcnt(0)"
        : "=&v"(a), "=&v"(b), "=&v"(c), "=&v"(d), "=&v"(e)
        : "v"(g0), "v"(g1), "v"(g2), "v"(g3), "v"(g4)
        : "memory");
}

// producer slice: 3 f4 for batch b, 3 f4 for batch b+1 (stride 2400 B)
__device__ __forceinline__ void ldg6_slice(const float4* base,
                                           float4& a, float4& b, float4& c,
                                           float4& d, float4& e, float4& f) {
    asm volatile(
        "global_load_dwordx4 %0, %6, off sc0 sc1\n\t"
        "global_load_dwordx4 %1, %6, off offset:16 sc0 sc1\n\t"
        "global_load_dwordx4 %2, %6, off offset:32 sc0 sc1\n\t"
        "global_load_dwordx4 %3, %6, off offset:2400 sc0 sc1\n\t"
        "global_load_dwordx4 %4, %6, off offset:2416 sc0 sc1\n\t"
        "global_load_dwordx4 %5, %6, off offset:2432 sc0 sc1\n\t"
        "s_waitcnt vmcnt(0)"
        : "=&v"(a), "=&v"(b), "=&v"(c), "=&v"(d), "=&v"(e), "=&v"(f)
        : "v"(base) : "memory");
}

__device__ __forceinline__ void stg_bypass(float* p, float v) {
    asm volatile("global_store_dword %0, %1, off sc0 sc1"
                 :: "v"(p), "v"(v) : "memory");
}

__device__ __forceinline__ float sigm_f(float v) {
    return 1.f / (1.f + __expf(-v));
}
__device__ __forceinline__ float tanh_f(float v) {
    return 1.f - 2.f / (__expf(2.f * v) + 1.f);
}

// fold CNT*2 partial sums down to CNT across lane-pairs (kh ^ MASK).
template<int MASK, int CNT>
__device__ __forceinline__ void fold(float* v, int kh) {
    const bool hi = (kh & MASK) != 0;
    #pragma unroll
    for (int i = 0; i < CNT; ++i) {
        float send = hi ? v[i] : v[i + CNT];
        float recv = __shfl_xor(send, MASK);
        v[i] = (hi ? v[i + CNT] : v[i]) + recv;
    }
}

extern "C" __global__ void __launch_bounds__(BLOCK, 2)
lstm_main(const float* __restrict__ x, const float* __restrict__ hs0,
          const float* __restrict__ cs0, const float* __restrict__ W_ih,
          const float* __restrict__ W_hh, const float* __restrict__ b_ih,
          const float* __restrict__ b_hh, float* __restrict__ hbuf,
          unsigned int* __restrict__ flags)
{
    extern __shared__ float lds[];
    float4* h4l  = (float4*)lds;          // [2400] = [16 b][150 f4], no pad
    float*  g_lds = lds + 4 * HB4;        // [48 rows][16 b] gate sums

    const int wg   = blockIdx.x;
    const int cg   = wg % CG;             // cell-group
    const int sg   = wg / CG;             // batch-group
    const int tid  = threadIdx.x;
    const int w    = tid >> 6;            // wave 0..7
    const int lane = tid & 63;
    const int bh   = lane >> 5;           // batch half (0: b0-7, 1: b8-15)
    const int kh   = lane & 31;           // k-chunk id (20 floats each)
    const int khc  = (kh < 30) ? kh : 29; // clamp idle lanes to valid addrs
    const int b0   = sg * BW;

    // ---- one-time: W_hh rows 6w..6w+5, k-chunk khc*20..+19 -> f2 registers ----
    // row r (0..47) <-> (gate g = r/12, local cell c = r%12), cell = cg*12+c.
    f2v Wr2[6][10];
    #pragma unroll
    for (int r = 0; r < 6; ++r) {
        const int row = 6 * w + r;
        const int g   = row / 12, c = row % 12;
        const float* wrow = W_hh + ((size_t)g * HH + cg * CPW + c) * HH + khc * 20;
        #pragma unroll
        for (int j = 0; j < 5; ++j) {
            float4 t4 = (kh < 30) ? *(const float4*)(wrow + 4 * j)
                                  : make_float4(0.f, 0.f, 0.f, 0.f);
            Wr2[r][2 * j]     = (f2v){t4.x, t4.y};
            Wr2[r][2 * j + 1] = (f2v){t4.z, t4.w};
        }
    }

    // ---- pointwise-lane constants (tid<192 owns (cell c=tid>>4, batch b=tid&15)) ----
    float wihv[4], biasv[4], cst = 0.f;
    const int pc = tid >> 4, pb = tid & 15;
    const int cell = cg * CPW + pc;            // valid when tid<192
    const int bglob = b0 + pb;
    if (tid < 192) {
        #pragma unroll
        for (int g = 0; g < 4; ++g) {
            const int grow = g * HH + cell;
            wihv[g]  = W_ih[grow];
            biasv[g] = b_ih[grow] + b_hh[grow];
        }
        cst = cs0[(size_t)bglob * HH + cell];
    }

    // t=0 stage indices (linear): f4 idx = b*150 + col
    const int i0 = tid, i1 = tid + 512, i2 = tid + 1024, i3 = tid + 1536;
    const int i4 = (tid + 2048 < HB4) ? tid + 2048 : HB4 - 1;

    // fused-stage constants (tid<400): producer sp = tid%50, batch pair tid/50
    // -> consecutive lanes write LDS at 12-dword stride: each 8-lane group
    //    covers all 32 banks exactly once (conflict-free phases).
    const int sp  = tid % 50;              // producer cell-group 0..49
    const int bsl = tid / 50;              // batch pair 0..7 (tid<400)
    const unsigned int* pflag = &flags[(sg * CG + sp) * 16];
    const int pdst = (2 * bsl) * 150 + 3 * sp;   // LDS f4 index, batch 2*bsl

    unsigned int* myflag = &flags[wg * 16];

    for (int t = 0; t < TT; ++t) {
        // x prefetch (cached, read-only)
        float xv = 0.f;
        if (tid < 192) xv = x[(size_t)bglob * TT + t];

        // ---- stage h[16][600] -> LDS ----
        if (t == 0) {
            const float4* s4 = (const float4*)hs0 + (size_t)b0 * 150;
            float4 v0, v1, v2, v3, v4;
            ldg5_bypass(s4 + i0, s4 + i1, s4 + i2, s4 + i3, s4 + i4,
                        v0, v1, v2, v3, v4);
            h4l[i0] = v0; h4l[i1] = v1; h4l[i2] = v2; h4l[i3] = v3; h4l[i4] = v4;
        } else if (tid < 400) {
            // fused wait+stage: poll MY producer (count >= 192*t), then pull
            const unsigned thr = 192u * (unsigned)t;
            while (__hip_atomic_load(pflag, __ATOMIC_RELAXED,
                                     __HIP_MEMORY_SCOPE_AGENT) < thr)
                __builtin_amdgcn_s_sleep(1);
            const float4* src = (const float4*)(hbuf + (size_t)(t & 1) * BB * HH
                + (size_t)(b0 + 2 * bsl) * HH + CPW * sp);
            float4 r0, r1, r2, r3, r4, r5;
            ldg6_slice(src, r0, r1, r2, r3, r4, r5);
            h4l[pdst]       = r0; h4l[pdst + 1]       = r1; h4l[pdst + 2]       = r2;
            h4l[pdst + 150] = r3; h4l[pdst + 150 + 1] = r4; h4l[pdst + 150 + 2] = r5;
        }
        __syncthreads();

        // ---- GEMV via packed f32 FMA: acc2[r][bi] over even/odd k pairs ----
        float v[48];
        {
            f2v acc2[6][8];
            #pragma unroll
            for (int r = 0; r < 6; ++r)
                #pragma unroll
                for (int bi = 0; bi < 8; ++bi)
                    acc2[r][bi] = (f2v){0.f, 0.f};

            const float* hf_base = lds + (size_t)bh * 8 * 600 + khc * 20;
            #pragma unroll
            for (int bi = 0; bi < 8; ++bi) {
                const f2v* hb2 = (const f2v*)(hf_base + bi * 600);
                f2v h2[10];
                #pragma unroll
                for (int j = 0; j < 10; ++j) h2[j] = hb2[j];
                #pragma unroll
                for (int r = 0; r < 6; ++r)
                    #pragma unroll
                    for (int j = 0; j < 10; ++j)
                        acc2[r][bi] = __builtin_elementwise_fma(Wr2[r][j],
                                                                h2[j],
                                                                acc2[r][bi]);
            }
            #pragma unroll
            for (int r = 0; r < 6; ++r)
                #pragma unroll
                for (int bi = 0; bi < 8; ++bi)
                    v[r * 8 + bi] = acc2[r][bi][0] + acc2[r][bi][1];
        }

        // ---- folding reduction over the 32 kh-lanes: 48 -> 24 -> 12 -> 6 -> 3 ----
        fold<16, 24>(v, kh);
        fold<8, 12>(v, kh);
        fold<4, 6>(v, kh);
        fold<2, 3>(v, kh);
        #pragma unroll
        for (int i = 0; i < 3; ++i)
            v[i] += __shfl_xor(v[i], 1);

        // ---- gather: even-kh lanes write their 3 final sums ----
        // value id = 3*(kh>>1)+s = rowl*8+bi  (rowl 0..5, bi 0..7)
        if (!(kh & 1)) {
            const int vb = 3 * (kh >> 1);
            #pragma unroll
            for (int s = 0; s < 3; ++s) {
                const int val = vb + s;
                const int rowl = val >> 3, bi = val & 7;
                g_lds[(6 * w + rowl) * 16 + bh * 8 + bi] = v[s];
            }
        }
        __syncthreads();

        // ---- pointwise LSTM update (192 lanes): store h, drain own wave,
        //      then wave-coalesced atomicAdd to the flag (no extra barrier) ----
        float* hdst = hbuf + (size_t)((t + 1) & 1) * BB * HH;
        if (tid < 192) {
            const float gi = g_lds[(0 * 12 + pc) * 16 + pb] + xv * wihv[0] + biasv[0];
            const float gf = g_lds[(1 * 12 + pc) * 16 + pb] + xv * wihv[1] + biasv[1];
            const float gg = g_lds[(2 * 12 + pc) * 16 + pb] + xv * wihv[2] + biasv[2];
            const float go = g_lds[(3 * 12 + pc) * 16 + pb] + xv * wihv[3] + biasv[3];
            const float cn = sigm_f(gf) * cst + sigm_f(gi) * tanh_f(gg);
            cst = cn;
            stg_bypass(&hdst[(size_t)bglob * HH + cell], sigm_f(go) * tanh_f(cn));
            asm volatile("s_waitcnt vmcnt(0)" ::: "memory");  // own wave's h in IF$
            atomicAdd(myflag, 1u);   // device-scope, wave-coalesced (m20)
        }
        // no barrier: next iteration's stage touches h4l only (g_lds reads done),
        // and the stage-barrier at the top of t+1 orders everything else.
    }
}

// final projection: out[b,o] = h_T[b,:] @ W_out[o,:] + b_out[o]
extern "C" __global__ void lstm_out(const float* __restrict__ hbuf0,
                                    const float* __restrict__ W_out,
                                    const float* __restrict__ b_out,
                                    float* __restrict__ out)
{
    int b = blockIdx.x;
    int lane = threadIdx.x;
    float acc[10] = {};
    for (int k = lane; k < HH; k += 64) {
        float hv = hbuf0[(size_t)b * HH + k];
        #pragma unroll
        for (int o = 0; o < 10; ++o)
            acc[o] += hv * W_out[(size_t)o * HH + k];
    }
    #pragma unroll
    for (int o = 0; o < 10; ++o) {
        float v = acc[o];
        for (int off = 32; off > 0; off >>= 1) v += __shfl_down(v, off);
        if (lane == 0) out[b * 10 + o] = v + b_out[o];
    }
}

extern "C" void kernel_launch(void* const* d_in, const int* in_sizes, int n_in,
                              void* d_out, int out_size, void* d_ws, size_t ws_size,
                              hipStream_t stream)
{
    const float* x     = (const float*)d_in[0];
    const float* hs0   = (const float*)d_in[1];
    const float* cs0   = (const float*)d_in[2];
    const float* W_ih  = (const float*)d_in[3];
    const float* W_hh  = (const float*)d_in[4];
    const float* b_ih  = (const float*)d_in[5];
    const float* b_hh  = (const float*)d_in[6];
    const float* W_out = (const float*)d_in[7];
    const float* b_out = (const float*)d_in[8];
    float* out = (float*)d_out;

    // workspace: hbuf[2][64][600] f32, then flags[200] spaced 64 B
    float* hbuf = (float*)d_ws;
    unsigned int* flags = (unsigned int*)((char*)d_ws + (size_t)2 * BB * HH * sizeof(float));

    hipFuncSetAttribute((const void*)lstm_main,
                        hipFuncAttributeMaxDynamicSharedMemorySize, LDS_BYTES);

    hipMemsetAsync(flags, 0, NWG * 16 * sizeof(unsigned int), stream);
    hipLaunchKernelGGL(lstm_main, dim3(NWG), dim3(BLOCK), LDS_BYTES, stream,
                       x, hs0, cs0, W_ih, W_hh, b_ih, b_hh, hbuf, flags);
    // t=783 writes hbuf[(784)&1] = hbuf[0]
    hipLaunchKernelGGL(lstm_out, dim3(BB), dim3(64), 0, stream,
                       hbuf, W_out, b_out, out);
}

// Round 11
// 4499.265 us; speedup vs baseline: 1.6297x; 1.6297x over previous
//
#include <hip/hip_runtime.h>
#include <math.h>

// LSTM: B=64, T=784, I=1, H=600.
// r4 base EXACTLY (proven 4.3ms, 0 bank conflicts) + ONE change: pk-FMA GEMV
// (v_pk_fma_f32 via f2v, r9-verified to halve VALU busy time). LDS read/write
// addressing byte-identical to r4 (b128, zero-conflict measured).
// 200 WGs = 50 cell-groups x 4 batch-groups. 12 cells x 16 batches per WG.
#define BB 64
#define TT 784
#define HH 600
#define CG 50           // cell-groups
#define SGN 4           // batch-groups
#define CPW 12          // cells per WG  -> 48 gate-rows
#define BW 16           // batches per WG
#define NWG (CG*SGN)    // 200
#define BLOCK 512       // 8 waves; wave owns 6 gate-rows; lane=(bh:2 x kh:32)
#define HB4 (BW*150)    // 2400 float4 of h per WG
#define LDS_BYTES (84*1024)   // force 1 WG/CU

typedef float f2v __attribute__((ext_vector_type(2)));

// five pipelined cache-bypassing 16B loads (one IF$ latency)
__device__ __forceinline__ void ldg5_bypass(const float4* g0, const float4* g1,
                                            const float4* g2, const float4* g3,
                                            const float4* g4,
                                            float4& a, float4& b, float4& c,
                                            float4& d, float4& e) {
    asm volatile(
        "global_load_dwordx4 %0, %5, off sc0 sc1\n\t"
        "global_load_dwordx4 %1, %6, off sc0 sc1\n\t"
        "global_load_dwordx4 %2, %7, off sc0 sc1\n\t"
        "global_load_dwordx4 %3, %8, off sc0 sc1\n\t"
        "global_load_dwordx4 %4, %9, off sc0 sc1\n\t"
        "s_waitcnt vmcnt(0)"
        : "=&v"(a), "=&v"(b), "=&v"(c), "=&v"(d), "=&v"(e)
        : "v"(g0), "v"(g1), "v"(g2), "v"(g3), "v"(g4)
        : "memory");
}

__device__ __forceinline__ void stg_bypass(float* p, float v) {
    asm volatile("global_store_dword %0, %1, off sc0 sc1"
                 :: "v"(p), "v"(v) : "memory");
}

__device__ __forceinline__ float sigm_f(float v) {
    return 1.f / (1.f + __expf(-v));
}
__device__ __forceinline__ float tanh_f(float v) {
    return 1.f - 2.f / (__expf(2.f * v) + 1.f);
}

// fold CNT*2 partial sums down to CNT across lane-pairs (kh ^ MASK).
template<int MASK, int CNT>
__device__ __forceinline__ void fold(float* v, int kh) {
    const bool hi = (kh & MASK) != 0;
    #pragma unroll
    for (int i = 0; i < CNT; ++i) {
        float send = hi ? v[i] : v[i + CNT];
        float recv = __shfl_xor(send, MASK);
        v[i] = (hi ? v[i + CNT] : v[i]) + recv;
    }
}

extern "C" __global__ void __launch_bounds__(BLOCK, 2)
lstm_main(const float* __restrict__ x, const float* __restrict__ hs0,
          const float* __restrict__ cs0, const float* __restrict__ W_ih,
          const float* __restrict__ W_hh, const float* __restrict__ b_ih,
          const float* __restrict__ b_hh, float* __restrict__ hbuf,
          unsigned int* __restrict__ flags)
{
    extern __shared__ float lds[];
    float4* h4l  = (float4*)lds;          // [2400] = [16 b][150 f4], no pad
    float*  g_lds = lds + 4 * HB4;        // [48 rows][16 b] gate sums

    const int wg   = blockIdx.x;
    const int cg   = wg % CG;             // cell-group
    const int sg   = wg / CG;             // batch-group
    const int tid  = threadIdx.x;
    const int w    = tid >> 6;            // wave 0..7
    const int lane = tid & 63;
    const int bh   = lane >> 5;           // batch half (0: b0-7, 1: b8-15)
    const int kh   = lane & 31;           // k-chunk id (20 floats each)
    const int khc  = (kh < 30) ? kh : 29; // clamp idle lanes to valid addrs
    const int b0   = sg * BW;

    // ---- one-time: W_hh rows 6w..6w+5, k-chunk khc*20..+19 -> f2 registers ----
    // row r (0..47) <-> (gate g = r/12, local cell c = r%12), cell = cg*12+c.
    f2v Wr2[6][10];
    #pragma unroll
    for (int r = 0; r < 6; ++r) {
        const int row = 6 * w + r;
        const int g   = row / 12, c = row % 12;
        const float* wrow = W_hh + ((size_t)g * HH + cg * CPW + c) * HH + khc * 20;
        #pragma unroll
        for (int j = 0; j < 5; ++j) {
            float4 t4 = (kh < 30) ? *(const float4*)(wrow + 4 * j)
                                  : make_float4(0.f, 0.f, 0.f, 0.f);
            Wr2[r][2 * j]     = (f2v){t4.x, t4.y};
            Wr2[r][2 * j + 1] = (f2v){t4.z, t4.w};
        }
    }

    // ---- pointwise-lane constants (tid<192 owns (cell c=tid>>4, batch b=tid&15)) ----
    float wihv[4], biasv[4], cst = 0.f;
    const int pc = tid >> 4, pb = tid & 15;
    const int cell = cg * CPW + pc;            // valid when tid<192
    const int bglob = b0 + pb;
    if (tid < 192) {
        #pragma unroll
        for (int g = 0; g < 4; ++g) {
            const int grow = g * HH + cell;
            wihv[g]  = W_ih[grow];
            biasv[g] = b_ih[grow] + b_hh[grow];
        }
        cst = cs0[(size_t)bglob * HH + cell];
    }

    // stage indices (linear in both src and LDS): f4 idx = b*150 + col
    const int i0 = tid, i1 = tid + 512, i2 = tid + 1024, i3 = tid + 1536;
    const int i4 = (tid + 2048 < HB4) ? tid + 2048 : HB4 - 1;

    unsigned int* myflag = &flags[wg * 16];

    for (int t = 0; t < TT; ++t) {
        // x prefetch (cached, read-only)
        float xv = 0.f;
        if (tid < 192) xv = x[(size_t)bglob * TT + t];

        // ---- wait for all 50 producers of our batch-group (sleep-backoff) ----
        if (t > 0) {
            if (tid < CG) {
                const unsigned int* f = &flags[(sg * CG + tid) * 16];
                while (__hip_atomic_load(f, __ATOMIC_RELAXED,
                                         __HIP_MEMORY_SCOPE_AGENT) < (unsigned)t)
                    __builtin_amdgcn_s_sleep(1);
            }
        }
        __syncthreads();

        // ---- stage h[16][600] -> LDS via 5 pipelined IF$-bypass loads ----
        {
            const float* hsrc = (t == 0) ? hs0 : (hbuf + (size_t)(t & 1) * BB * HH);
            const float4* s4 = (const float4*)hsrc + (size_t)b0 * 150;
            float4 v0, v1, v2, v3, v4;
            ldg5_bypass(s4 + i0, s4 + i1, s4 + i2, s4 + i3, s4 + i4,
                        v0, v1, v2, v3, v4);
            h4l[i0] = v0; h4l[i1] = v1; h4l[i2] = v2; h4l[i3] = v3; h4l[i4] = v4;
        }
        __syncthreads();

        // ---- GEMV via packed f32 FMA; h read as b128 (r4 zero-conflict addr) ----
        float v[48];
        {
            f2v acc2[6][8];
            #pragma unroll
            for (int r = 0; r < 6; ++r)
                #pragma unroll
                for (int bi = 0; bi < 8; ++bi)
                    acc2[r][bi] = (f2v){0.f, 0.f};

            const float4* hb_base = h4l + (size_t)bh * 8 * 150 + khc * 5;
            #pragma unroll
            for (int bi = 0; bi < 8; ++bi) {
                const float4* hb = hb_base + bi * 150;
                float4 hv[5];
                hv[0] = hb[0]; hv[1] = hb[1]; hv[2] = hb[2];
                hv[3] = hb[3]; hv[4] = hb[4];
                const f2v* h2 = (const f2v*)hv;   // register-aliased pairs
                #pragma unroll
                for (int r = 0; r < 6; ++r)
                    #pragma unroll
                    for (int j = 0; j < 10; ++j)
                        acc2[r][bi] = __builtin_elementwise_fma(Wr2[r][j],
                                                                h2[j],
                                                                acc2[r][bi]);
            }
            #pragma unroll
            for (int r = 0; r < 6; ++r)
                #pragma unroll
                for (int bi = 0; bi < 8; ++bi)
                    v[r * 8 + bi] = acc2[r][bi][0] + acc2[r][bi][1];
        }

        // ---- folding reduction over the 32 kh-lanes: 48 -> 24 -> 12 -> 6 -> 3 ----
        fold<16, 24>(v, kh);
        fold<8, 12>(v, kh);
        fold<4, 6>(v, kh);
        fold<2, 3>(v, kh);
        #pragma unroll
        for (int i = 0; i < 3; ++i)
            v[i] += __shfl_xor(v[i], 1);

        // ---- gather: even-kh lanes write their 3 final sums ----
        // value id = 3*(kh>>1)+s = rowl*8+bi  (rowl 0..5, bi 0..7)
        if (!(kh & 1)) {
            const int vb = 3 * (kh >> 1);
            #pragma unroll
            for (int s = 0; s < 3; ++s) {
                const int val = vb + s;
                const int rowl = val >> 3, bi = val & 7;
                g_lds[(6 * w + rowl) * 16 + bh * 8 + bi] = v[s];
            }
        }
        __syncthreads();

        // ---- pointwise LSTM cell update (192 lanes) + bypass-store h ----
        float* hdst = hbuf + (size_t)((t + 1) & 1) * BB * HH;
        if (tid < 192) {
            const float gi = g_lds[(0 * 12 + pc) * 16 + pb] + xv * wihv[0] + biasv[0];
            const float gf = g_lds[(1 * 12 + pc) * 16 + pb] + xv * wihv[1] + biasv[1];
            const float gg = g_lds[(2 * 12 + pc) * 16 + pb] + xv * wihv[2] + biasv[2];
            const float go = g_lds[(3 * 12 + pc) * 16 + pb] + xv * wihv[3] + biasv[3];
            const float cn = sigm_f(gf) * cst + sigm_f(gi) * tanh_f(gg);
            cst = cn;
            stg_bypass(&hdst[(size_t)bglob * HH + cell], sigm_f(go) * tanh_f(cn));
        }
        asm volatile("s_waitcnt vmcnt(0)" ::: "memory");
        __syncthreads();   // all waves' h stores are in IF$ before flag
        if (tid == 0)
            __hip_atomic_store(myflag, (unsigned)(t + 1), __ATOMIC_RELAXED,
                               __HIP_MEMORY_SCOPE_AGENT);
    }
}

// final projection: out[b,o] = h_T[b,:] @ W_out[o,:] + b_out[o]
extern "C" __global__ void lstm_out(const float* __restrict__ hbuf0,
                                    const float* __restrict__ W_out,
                                    const float* __restrict__ b_out,
                                    float* __restrict__ out)
{
    int b = blockIdx.x;
    int lane = threadIdx.x;
    float acc[10] = {};
    for (int k = lane; k < HH; k += 64) {
        float hv = hbuf0[(size_t)b * HH + k];
        #pragma unroll
        for (int o = 0; o < 10; ++o)
            acc[o] += hv * W_out[(size_t)o * HH + k];
    }
    #pragma unroll
    for (int o = 0; o < 10; ++o) {
        float v = acc[o];
        for (int off = 32; off > 0; off >>= 1) v += __shfl_down(v, off);
        if (lane == 0) out[b * 10 + o] = v + b_out[o];
    }
}

extern "C" void kernel_launch(void* const* d_in, const int* in_sizes, int n_in,
                              void* d_out, int out_size, void* d_ws, size_t ws_size,
                              hipStream_t stream)
{
    const float* x     = (const float*)d_in[0];
    const float* hs0   = (const float*)d_in[1];
    const float* cs0   = (const float*)d_in[2];
    const float* W_ih  = (const float*)d_in[3];
    const float* W_hh  = (const float*)d_in[4];
    const float* b_ih  = (const float*)d_in[5];
    const float* b_hh  = (const float*)d_in[6];
    const float* W_out = (const float*)d_in[7];
    const float* b_out = (const float*)d_in[8];
    float* out = (float*)d_out;

    // workspace: hbuf[2][64][600] f32, then flags[200] spaced 64 B
    float* hbuf = (float*)d_ws;
    unsigned int* flags = (unsigned int*)((char*)d_ws + (size_t)2 * BB * HH * sizeof(float));

    hipFuncSetAttribute((const void*)lstm_main,
                        hipFuncAttributeMaxDynamicSharedMemorySize, LDS_BYTES);

    hipMemsetAsync(flags, 0, NWG * 16 * sizeof(unsigned int), stream);
    hipLaunchKernelGGL(lstm_main, dim3(NWG), dim3(BLOCK), LDS_BYTES, stream,
                       x, hs0, cs0, W_ih, W_hh, b_ih, b_hh, hbuf, flags);
    // t=783 writes hbuf[(784)&1] = hbuf[0]
    hipLaunchKernelGGL(lstm_out, dim3(BB), dim3(64), 0, stream,
                       hbuf, W_out, b_out, out);
}